// Round 1
// baseline (351.005 us; speedup 1.0000x reference)
//
#include <hip/hip_runtime.h>
#include <math.h>

#define B_   8
#define N_   16384
#define M_   64
#define C_   192
#define RC_  16

// ---------------------------------------------------------------------------
// K1: v[b,m,c] = dict[b,m,:] @ wv_w[:,c] + wv_b[c]
// ---------------------------------------------------------------------------
__global__ __launch_bounds__(256) void k_v_kernel(
    const float* __restrict__ dict, const float* __restrict__ wv_w,
    const float* __restrict__ wv_b, float* __restrict__ ws_v)
{
    const int idx = blockIdx.x * 256 + threadIdx.x;   // (b*64+m)*192 + c
    const int c   = idx % C_;
    const int row = idx / C_;
    const float* dr = dict + row * C_;
    float acc = wv_b[c];
    #pragma unroll 4
    for (int d = 0; d < C_; ++d)
        acc = fmaf(dr[d], wv_w[d * C_ + c], acc);
    ws_v[idx] = acc;
}

// ---------------------------------------------------------------------------
// K2: k[b,m,:] = l2norm(layernorm(dict[b,m,:] @ wk_w + wk_b))
//     one block per b; thread = (m, j4); j4 owns 4 of 16 components.
// ---------------------------------------------------------------------------
__global__ __launch_bounds__(256) void k_k_kernel(
    const float* __restrict__ dict, const float* __restrict__ wk_w,
    const float* __restrict__ wk_b, const float* __restrict__ kn_g,
    const float* __restrict__ kn_b, float* __restrict__ ws_k)
{
    const int b  = blockIdx.x;
    const int m  = threadIdx.x >> 2;
    const int j4 = threadIdx.x & 3;
    const int c0 = j4 * 4;
    const float* dr = dict + (b * M_ + m) * C_;

    float a0 = wk_b[c0+0], a1 = wk_b[c0+1], a2 = wk_b[c0+2], a3 = wk_b[c0+3];
    #pragma unroll 4
    for (int d4 = 0; d4 < C_/4; ++d4) {
        const float4 xv = ((const float4*)dr)[d4];
        const float4 w0 = *(const float4*)&wk_w[(d4*4+0)*RC_ + c0];
        const float4 w1 = *(const float4*)&wk_w[(d4*4+1)*RC_ + c0];
        const float4 w2 = *(const float4*)&wk_w[(d4*4+2)*RC_ + c0];
        const float4 w3 = *(const float4*)&wk_w[(d4*4+3)*RC_ + c0];
        a0 = fmaf(xv.x, w0.x, a0); a1 = fmaf(xv.x, w0.y, a1); a2 = fmaf(xv.x, w0.z, a2); a3 = fmaf(xv.x, w0.w, a3);
        a0 = fmaf(xv.y, w1.x, a0); a1 = fmaf(xv.y, w1.y, a1); a2 = fmaf(xv.y, w1.z, a2); a3 = fmaf(xv.y, w1.w, a3);
        a0 = fmaf(xv.z, w2.x, a0); a1 = fmaf(xv.z, w2.y, a1); a2 = fmaf(xv.z, w2.z, a2); a3 = fmaf(xv.z, w2.w, a3);
        a0 = fmaf(xv.w, w3.x, a0); a1 = fmaf(xv.w, w3.y, a1); a2 = fmaf(xv.w, w3.z, a2); a3 = fmaf(xv.w, w3.w, a3);
    }
    float s  = a0 + a1 + a2 + a3;
    float ss = a0*a0 + a1*a1 + a2*a2 + a3*a3;
    s  += __shfl_xor(s, 1);  s  += __shfl_xor(s, 2);
    ss += __shfl_xor(ss, 1); ss += __shfl_xor(ss, 2);
    const float mu   = s * (1.0f/16.0f);
    const float var  = ss * (1.0f/16.0f) - mu*mu;
    const float rstd = rsqrtf(var + 1e-5f);
    const float4 g4 = *(const float4*)&kn_g[c0];
    const float4 b4 = *(const float4*)&kn_b[c0];
    float y0 = (a0 - mu) * rstd * g4.x + b4.x;
    float y1 = (a1 - mu) * rstd * g4.y + b4.y;
    float y2 = (a2 - mu) * rstd * g4.z + b4.z;
    float y3 = (a3 - mu) * rstd * g4.w + b4.w;
    float n2 = y0*y0 + y1*y1 + y2*y2 + y3*y3;
    n2 += __shfl_xor(n2, 1); n2 += __shfl_xor(n2, 2);
    const float inv = 1.0f / fmaxf(sqrtf(n2), 1e-12f);
    float4 o; o.x = y0*inv; o.y = y1*inv; o.z = y2*inv; o.w = y3*inv;
    *(float4*)&ws_k[(b * M_ + m) * RC_ + c0] = o;
}

// ---------------------------------------------------------------------------
// K3: vg = gelu(conv3x1_depthwise(v) + conv_b).  Only center column of the
//     3x3 kernel touches real data (image width is 1 with padding 1).
// ---------------------------------------------------------------------------
__global__ __launch_bounds__(256) void k_conv_kernel(
    const float* __restrict__ ws_v, const float* __restrict__ conv_w,
    const float* __restrict__ conv_b, float* __restrict__ ws_vg)
{
    const int idx = blockIdx.x * 256 + threadIdx.x;  // (b*64+m)*192 + c
    const int c   = idx % C_;
    const int m   = (idx / C_) % M_;
    const float ctr = ws_v[idx];
    const float up  = (m > 0)      ? ws_v[idx - C_] : 0.0f;
    const float dn  = (m < M_ - 1) ? ws_v[idx + C_] : 0.0f;
    const float w0 = conv_w[c*9 + 1];   // kh=0, kw=1
    const float w1 = conv_w[c*9 + 4];   // kh=1, kw=1
    const float w2 = conv_w[c*9 + 7];   // kh=2, kw=1
    float t = conv_b[c];
    t = fmaf(up, w0, t); t = fmaf(ctr, w1, t); t = fmaf(dn, w2, t);
    // exact GELU: 0.5*x*(1+erf(x/sqrt(2)))
    ws_vg[idx] = 0.5f * t * (1.0f + erff(t * 0.70710678118654752f));
}

// ---------------------------------------------------------------------------
// K4: fused main kernel. 64 rows per block; thread = (r = tid>>2, j4 = tid&3).
//   (a) q = l2norm(LN(x@wq+b))            (j4 owns 4 of 16 comps, shfl stats)
//   (b) attn = softmax(q.k / max(T,.5))    (j4 owns 16 of 64 m)
//   (c) out = attn @ vg                    (j4 owns 48 of 192 ch, interleaved)
// ---------------------------------------------------------------------------
__global__ __launch_bounds__(256, 2) void k_main_kernel(
    const float* __restrict__ x, const float* __restrict__ ws_k,
    const float* __restrict__ ws_vg,
    const float* __restrict__ wq_w, const float* __restrict__ wq_b,
    const float* __restrict__ qn_g, const float* __restrict__ qn_b,
    const float* __restrict__ temp,
    float* __restrict__ out, float* __restrict__ attn_out)
{
    __shared__ float vg_s[M_ * C_];        // 48 KB
    __shared__ float attn_s[M_ * 68];      // 17 KB, stride 68: f16B-aligned, 2-way max
    __shared__ float q_s[M_ * 20];         // 5 KB, stride 20 breaks bank aliasing
    __shared__ float k_s[M_ * RC_];        // 4 KB

    const int tid = threadIdx.x;
    const int b   = blockIdx.x >> 8;
    const int n0  = (blockIdx.x & 255) * M_;

    // ---- stage vg (12288 f) + k (1024 f) into LDS, coalesced float4 ----
    {
        const float4* src = (const float4*)(ws_vg + b * (M_ * C_));
        float4*       dst = (float4*)vg_s;
        #pragma unroll
        for (int i = 0; i < 12; ++i)
            dst[tid + 256 * i] = src[tid + 256 * i];
        ((float4*)k_s)[tid] = ((const float4*)(ws_k + b * (M_ * RC_)))[tid];
    }

    const int r  = tid >> 2;
    const int j4 = tid & 3;
    const int c0 = j4 * 4;

    // ---- phase (a): q projection + LN + l2norm ----
    const float* xr = x + (size_t)(b * N_ + n0 + r) * C_;
    float a0 = wq_b[c0+0], a1 = wq_b[c0+1], a2 = wq_b[c0+2], a3 = wq_b[c0+3];
    #pragma unroll 4
    for (int d4 = 0; d4 < C_/4; ++d4) {
        const float4 xv = ((const float4*)xr)[d4];
        // all 4 j4 slices of row d live in one 64B line -> broadcast-coalesced
        const float4 w0 = *(const float4*)&wq_w[(d4*4+0)*RC_ + c0];
        const float4 w1 = *(const float4*)&wq_w[(d4*4+1)*RC_ + c0];
        const float4 w2 = *(const float4*)&wq_w[(d4*4+2)*RC_ + c0];
        const float4 w3 = *(const float4*)&wq_w[(d4*4+3)*RC_ + c0];
        a0 = fmaf(xv.x, w0.x, a0); a1 = fmaf(xv.x, w0.y, a1); a2 = fmaf(xv.x, w0.z, a2); a3 = fmaf(xv.x, w0.w, a3);
        a0 = fmaf(xv.y, w1.x, a0); a1 = fmaf(xv.y, w1.y, a1); a2 = fmaf(xv.y, w1.z, a2); a3 = fmaf(xv.y, w1.w, a3);
        a0 = fmaf(xv.z, w2.x, a0); a1 = fmaf(xv.z, w2.y, a1); a2 = fmaf(xv.z, w2.z, a2); a3 = fmaf(xv.z, w2.w, a3);
        a0 = fmaf(xv.w, w3.x, a0); a1 = fmaf(xv.w, w3.y, a1); a2 = fmaf(xv.w, w3.z, a2); a3 = fmaf(xv.w, w3.w, a3);
    }
    {
        float s  = a0 + a1 + a2 + a3;
        float ss = a0*a0 + a1*a1 + a2*a2 + a3*a3;
        s  += __shfl_xor(s, 1);  s  += __shfl_xor(s, 2);
        ss += __shfl_xor(ss, 1); ss += __shfl_xor(ss, 2);
        const float mu   = s * (1.0f/16.0f);
        const float var  = ss * (1.0f/16.0f) - mu*mu;
        const float rstd = rsqrtf(var + 1e-5f);
        const float4 g4 = *(const float4*)&qn_g[c0];
        const float4 b4 = *(const float4*)&qn_b[c0];
        const float y0 = (a0 - mu) * rstd * g4.x + b4.x;
        const float y1 = (a1 - mu) * rstd * g4.y + b4.y;
        const float y2 = (a2 - mu) * rstd * g4.z + b4.z;
        const float y3 = (a3 - mu) * rstd * g4.w + b4.w;
        float n2 = y0*y0 + y1*y1 + y2*y2 + y3*y3;
        n2 += __shfl_xor(n2, 1); n2 += __shfl_xor(n2, 2);
        const float inv = 1.0f / fmaxf(sqrtf(n2), 1e-12f);
        float4 o; o.x = y0*inv; o.y = y1*inv; o.z = y2*inv; o.w = y3*inv;
        *(float4*)&q_s[r*20 + c0] = o;
    }

    __syncthreads();   // vg_s, k_s, q_s all visible

    // ---- phase (b): scores + softmax (thread owns m = j4*16 .. +15) ----
    {
        const float tinv = 1.0f / fmaxf(temp[0], 0.5f);
        const float4 q0 = *(const float4*)&q_s[r*20 + 0];
        const float4 q1 = *(const float4*)&q_s[r*20 + 4];
        const float4 q2 = *(const float4*)&q_s[r*20 + 8];
        const float4 q3 = *(const float4*)&q_s[r*20 + 12];
        float sc[16];
        #pragma unroll
        for (int mm = 0; mm < 16; ++mm) {
            const int m = j4*16 + mm;
            const float4 k0 = *(const float4*)&k_s[m*RC_ + 0];
            const float4 k1 = *(const float4*)&k_s[m*RC_ + 4];
            const float4 k2 = *(const float4*)&k_s[m*RC_ + 8];
            const float4 k3 = *(const float4*)&k_s[m*RC_ + 12];
            float d = q0.x*k0.x;
            d = fmaf(q0.y, k0.y, d); d = fmaf(q0.z, k0.z, d); d = fmaf(q0.w, k0.w, d);
            d = fmaf(q1.x, k1.x, d); d = fmaf(q1.y, k1.y, d); d = fmaf(q1.z, k1.z, d); d = fmaf(q1.w, k1.w, d);
            d = fmaf(q2.x, k2.x, d); d = fmaf(q2.y, k2.y, d); d = fmaf(q2.z, k2.z, d); d = fmaf(q2.w, k2.w, d);
            d = fmaf(q3.x, k3.x, d); d = fmaf(q3.y, k3.y, d); d = fmaf(q3.z, k3.z, d); d = fmaf(q3.w, k3.w, d);
            sc[mm] = d * tinv;
        }
        float mx = sc[0];
        #pragma unroll
        for (int mm = 1; mm < 16; ++mm) mx = fmaxf(mx, sc[mm]);
        mx = fmaxf(mx, __shfl_xor(mx, 1)); mx = fmaxf(mx, __shfl_xor(mx, 2));
        float es = 0.0f;
        #pragma unroll
        for (int mm = 0; mm < 16; ++mm) { sc[mm] = expf(sc[mm] - mx); es += sc[mm]; }
        es += __shfl_xor(es, 1); es += __shfl_xor(es, 2);
        const float einv = 1.0f / es;
        float* aw = attn_out + (size_t)(b * N_ + n0 + r) * M_ + j4*16;
        #pragma unroll
        for (int mq = 0; mq < 4; ++mq) {
            float4 av;
            av.x = sc[mq*4+0]*einv; av.y = sc[mq*4+1]*einv;
            av.z = sc[mq*4+2]*einv; av.w = sc[mq*4+3]*einv;
            *(float4*)&attn_s[r*68 + j4*16 + mq*4] = av;
            ((float4*)aw)[mq] = av;
        }
    }

    __syncthreads();   // attn_s visible

    // ---- phase (c): out = attn @ vg  (thread: 48 interleaved channels) ----
    {
        float4 acc[12];
        #pragma unroll
        for (int cc = 0; cc < 12; ++cc) { acc[cc].x = 0.f; acc[cc].y = 0.f; acc[cc].z = 0.f; acc[cc].w = 0.f; }
        for (int m = 0; m < M_; ++m) {
            const float a = attn_s[r*68 + m];
            #pragma unroll
            for (int cc = 0; cc < 12; ++cc) {
                const float4 v = *(const float4*)&vg_s[m*C_ + cc*16 + c0];
                acc[cc].x = fmaf(a, v.x, acc[cc].x);
                acc[cc].y = fmaf(a, v.y, acc[cc].y);
                acc[cc].z = fmaf(a, v.z, acc[cc].z);
                acc[cc].w = fmaf(a, v.w, acc[cc].w);
            }
        }
        float* orow = out + (size_t)(b * N_ + n0 + r) * C_;
        #pragma unroll
        for (int cc = 0; cc < 12; ++cc)
            *(float4*)&orow[cc*16 + c0] = acc[cc];
    }
}

// ---------------------------------------------------------------------------
extern "C" void kernel_launch(void* const* d_in, const int* in_sizes, int n_in,
                              void* d_out, int out_size, void* d_ws, size_t ws_size,
                              hipStream_t stream) {
    const float* x      = (const float*)d_in[0];
    const float* dict   = (const float*)d_in[1];
    // d_in[2]=H, d_in[3]=W (unused: M-axis conv only)
    const float* wq_w   = (const float*)d_in[4];
    const float* wq_b   = (const float*)d_in[5];
    const float* wk_w   = (const float*)d_in[6];
    const float* wk_b   = (const float*)d_in[7];
    const float* wv_w   = (const float*)d_in[8];
    const float* wv_b   = (const float*)d_in[9];
    const float* qn_g   = (const float*)d_in[10];
    const float* qn_b   = (const float*)d_in[11];
    const float* kn_g   = (const float*)d_in[12];
    const float* kn_b   = (const float*)d_in[13];
    const float* conv_w = (const float*)d_in[14];
    const float* conv_b = (const float*)d_in[15];
    const float* temp   = (const float*)d_in[16];

    float* out  = (float*)d_out;                          // (B,N,192)
    float* attn = out + (size_t)B_ * N_ * C_;             // (B,N,64)

    float* ws_v  = (float*)d_ws;                          // B*M*C = 98304 f
    float* ws_vg = ws_v  + B_ * M_ * C_;                  // 98304 f
    float* ws_k  = ws_vg + B_ * M_ * C_;                  // 8192 f  (~800KB total)

    k_v_kernel   <<<B_ * M_ * C_ / 256, 256, 0, stream>>>(dict, wv_w, wv_b, ws_v);
    k_k_kernel   <<<B_,                 256, 0, stream>>>(dict, wk_w, wk_b, kn_g, kn_b, ws_k);
    k_conv_kernel<<<B_ * M_ * C_ / 256, 256, 0, stream>>>(ws_v, conv_w, conv_b, ws_vg);
    k_main_kernel<<<B_ * (N_ / M_),     256, 0, stream>>>(x, ws_k, ws_vg, wq_w, wq_b,
                                                          qn_g, qn_b, temp, out, attn);
}